// Round 23
// baseline (207.071 us; speedup 1.0000x reference)
//
#include <hip/hip_runtime.h>
#include <hip/hip_bf16.h>

#define NPATCH 15376       // 124*124 patches
#define NP     15488       // B rows padded: 121*128
#define NT     121         // B col-tiles (128 each)
#define ATILES 128         // A rows padded: 128*128 = 16384
#define TILE_SHORTS 12288  // 12*128*8 shorts per 128-row tile (24KB)
#define EPSA   1.30f       // acc-space margin; rigorous 2E ~= 1.16 (bf16 screen + f16 PM)
#define PMSTR  16384       // PMh row stride

typedef __attribute__((ext_vector_type(8))) __bf16 bf16x8;
typedef __attribute__((ext_vector_type(4))) float  f32x4;
typedef __attribute__((ext_vector_type(4))) _Float16 f16x4;
typedef float __attribute__((ext_vector_type(4), aligned(4))) f32x4u;  // 4B-aligned vec load

__device__ __forceinline__ unsigned short f2bf(float x) {
    __hip_bfloat16 h = __float2bfloat16(x);
    return *(unsigned short*)&h;
}
__device__ __forceinline__ float bf2f(unsigned short u) {
    __hip_bfloat16 h; *(unsigned short*)&h = u;
    return __bfloat162float(h);
}
__device__ __forceinline__ unsigned int fsort(float d) {   // monotone float->uint
    unsigned int b = __builtin_bit_cast(unsigned int, d);
    return (b & 0x80000000u) ? ~b : (b | 0x80000000u);
}
__device__ __forceinline__ float max3f(float a, float b, float c) {
    return fmaxf(fmaxf(a, b), c);   // clang fuses to v_max3_f32
}

// ---------- fused squared norms + RES/WLn init
__device__ __forceinline__ float patch_sq(const float* __restrict__ img, int p) {
    int pr = p / 124, pc = p - pr * 124;
    const float* base = img + pr * 128 + pc;
    float s = 0.f;
    #pragma unroll
    for (int ch = 0; ch < 3; ++ch)
        #pragma unroll
        for (int di = 0; di < 5; ++di)
            #pragma unroll
            for (int dj = 0; dj < 5; ++dj) {
                float v = base[ch * 16384 + di * 128 + dj];
                s = fmaf(v, v, s);
            }
    return s;
}
__global__ void sqnorm2(const float* __restrict__ crop, const float* __restrict__ orig,
                        float* __restrict__ X2, float* __restrict__ Y2,
                        unsigned int* __restrict__ WLn, unsigned long long* __restrict__ RES) {
    int p = blockIdx.x * 256 + threadIdx.x;
    if (p == 0) *WLn = 0;
    if (p < NP) {
        Y2[p] = (p < NPATCH) ? patch_sq(orig, p) : 3.0e38f;
    } else {
        int q = p - NP;
        if (q < NPATCH) { X2[q] = patch_sq(crop, q); RES[q] = 0xFFFFFFFFFFFFFFFFULL; }
    }
}

// ---------- pack both matrices: tile-major [tile][kslot12][row128][8] bf16.
__global__ void pack2(const float* __restrict__ crop, const float* __restrict__ orig,
                      unsigned short* __restrict__ Abig, unsigned short* __restrict__ Bbig,
                      const float* __restrict__ Y2) {
    int cid = blockIdx.x * 256 + threadIdx.x;
    const float* img;
    unsigned short* dst;
    bool isA;
    if (cid < ATILES * 1536) { img = crop; dst = Abig; isA = true; }
    else { cid -= ATILES * 1536; img = orig; dst = Bbig; isA = false; }
    int t = cid / 1536, rem = cid - t * 1536;
    int s = rem >> 7, r = rem & 127;
    int row = t * 128 + r;
    unsigned short ch8[8];
    #pragma unroll
    for (int e = 0; e < 8; ++e) {
        int k = s * 8 + e;
        unsigned short v = 0;
        if (k < 75) {
            if (row < NPATCH) {
                int c = k / 25, rem2 = k - c * 25;
                int di = rem2 / 5, dj = rem2 - di * 5;
                int pr = row / 124, pc = row - pr * 124;
                v = f2bf(img[c * 16384 + (pr + di) * 128 + (pc + dj)]);
            }
        } else if (k < 77) {
            if (isA) v = f2bf(-0.5f);
            else {
                float yv = Y2[row];
                unsigned short hi = f2bf(yv);
                v = (k == 75) ? hi : f2bf(yv - bf2f(hi));
            }
        }
        ch8[e] = v;
    }
    *(ulonglong2*)(dst + (size_t)cid * 8) = *(ulonglong2*)ch8;
}

// ---------- MFMA screen, barrier-free, TRIPLE-buffered B stream (2 tiles load-ahead)
__global__ __launch_bounds__(256, 2)
void dist_mfma6(const unsigned short* __restrict__ A, const unsigned short* __restrict__ B,
                _Float16* __restrict__ PMh) {
    __shared__ _Float16 stash[4][16][64];   // 8 KB, wave-private slices: no barriers

    const int tid = threadIdx.x, lane = tid & 63, wid = tid >> 6;
    const int l15 = lane & 15, l4 = lane >> 4;

    // 4 waves of a block share the same (cg, chunk) B stream (L1 reuse); wid -> rowgroup.
    const int b = blockIdx.x;                    // 0..1023
    const int cg = b & 1;
    const int chunk = (b >> 1) & 7;
    const int rowgroup = (b >> 4) * 4 + wid;     // 0..255 (64 rows each)
    const int t0 = chunk * 15 + (chunk ? 1 : 0);
    const int nt = chunk ? 15 : 16;              // 16 + 15*7 = 121

    bf16x8 a[4][3];
    {
        const int atile = rowgroup >> 1, rbase = (rowgroup & 1) * 64;
        const unsigned short* Ab =
            A + ((size_t)atile * 12 + l4) * 1024 + (size_t)(rbase + l15) * 8;
        #pragma unroll
        for (int mi = 0; mi < 4; ++mi)
            #pragma unroll
            for (int k3 = 0; k3 < 3; ++k3)
                a[mi][k3] = *(const bf16x8*)(Ab + k3 * 4096 + mi * 128);
    }

    const size_t cgofs = (size_t)cg * 512 + (size_t)l15 * 8;
    bf16x8 b0[12], b1[12], b2[12];

#define BLOAD(bank, tile)                                                         \
    {                                                                             \
        const unsigned short* _B = B + ((size_t)(tile) * 12 + l4) * 1024 + cgofs; \
        _Pragma("unroll")                                                         \
        for (int _ni = 0; _ni < 4; ++_ni)                                         \
            _Pragma("unroll")                                                     \
            for (int _k3 = 0; _k3 < 3; ++_k3)                                     \
                bank[_ni * 3 + _k3] = *(const bf16x8*)(_B + _k3 * 4096 + _ni * 128); \
    }

#define COMPUTE(bank, it)                                                         \
    {                                                                             \
        f32x4 acc[4][4];                                                          \
        _Pragma("unroll")                                                         \
        for (int _k3 = 0; _k3 < 3; ++_k3)                                         \
            _Pragma("unroll")                                                     \
            for (int _mi = 0; _mi < 4; ++_mi)                                     \
                _Pragma("unroll")                                                 \
                for (int _ni = 0; _ni < 4; ++_ni)                                 \
                    acc[_mi][_ni] = __builtin_amdgcn_mfma_f32_16x16x32_bf16(      \
                        bank[_ni * 3 + _k3], a[_mi][_k3],                         \
                        (_k3 == 0) ? (f32x4){0.f, 0.f, 0.f, 0.f} : acc[_mi][_ni], \
                        0, 0, 0);                                                 \
        _Pragma("unroll")                                                         \
        for (int _mi = 0; _mi < 4; ++_mi) {                                       \
            float _t0 = max3f(acc[_mi][0][0], acc[_mi][0][1], acc[_mi][0][2]);    \
            float _t1 = max3f(acc[_mi][0][3], acc[_mi][1][0], acc[_mi][1][1]);    \
            float _t2 = max3f(acc[_mi][1][2], acc[_mi][1][3], acc[_mi][2][0]);    \
            float _t3 = max3f(acc[_mi][2][1], acc[_mi][2][2], acc[_mi][2][3]);    \
            float _t4 = max3f(acc[_mi][3][0], acc[_mi][3][1], acc[_mi][3][2]);    \
            float _u0 = max3f(_t0, _t1, acc[_mi][3][3]);                          \
            float _u1 = max3f(_t2, _t3, _t4);                                     \
            float _m  = fmaxf(_u0, _u1);                                          \
            _m = fmaxf(_m, __shfl_xor(_m, 16));                                   \
            _m = fmaxf(_m, __shfl_xor(_m, 32));                                   \
            if (l4 == 0) stash[wid][it][_mi * 16 + l15] = (_Float16)_m;           \
        }                                                                         \
    }

    // 3-deep rotation, statically named banks (no runtime bank indexing)
    BLOAD(b0, t0);
    BLOAD(b1, t0 + 1);              // nt >= 15 always, safe
    int it = 0;
    while (true) {
        if (it + 2 < nt) BLOAD(b2, t0 + it + 2);
        COMPUTE(b0, it);
        ++it; if (it >= nt) break;
        if (it + 2 < nt) BLOAD(b0, t0 + it + 2);
        COMPUTE(b1, it);
        ++it; if (it >= nt) break;
        if (it + 2 < nt) BLOAD(b1, t0 + it + 2);
        COMPUTE(b2, it);
        ++it; if (it >= nt) break;
    }
#undef BLOAD
#undef COMPUTE

    for (int i2 = 0; i2 < nt; ++i2)
        PMh[(size_t)((t0 + i2) * 2 + cg) * PMSTR + rowgroup * 64 + lane] = stash[wid][i2][lane];
}

// ---------- flag: block = 256 rows; coalesced PMh reads; ONE global atomic per block
__global__ __launch_bounds__(256)
void flag_kernel(const _Float16* __restrict__ PMh,
                 unsigned int* __restrict__ WL, unsigned int* __restrict__ WLn) {
    __shared__ _Float16 cachev[NT][256];   // 61.9 KB (folded tile maxima)
    __shared__ int scan[256];
    __shared__ unsigned int sbase;

    const int tid = threadIdx.x;
    const int r = blockIdx.x * 256 + tid;
    const int rr = (r < NPATCH) ? r : (NPATCH - 1);

    float mt = -3.4e38f;
    for (int t = 0; t < NT; ++t) {
        float v0 = (float)PMh[(size_t)(2 * t) * PMSTR + rr];
        float v1 = (float)PMh[(size_t)(2 * t + 1) * PMSTR + rr];
        float v = fmaxf(v0, v1);
        cachev[t][tid] = (_Float16)v;
        mt = fmaxf(mt, v);
    }
    const float thr = mt - EPSA;

    int cnt = 0;
    if (r < NPATCH)
        for (int t = 0; t < NT; ++t)
            cnt += ((float)cachev[t][tid] >= thr) ? 1 : 0;

    scan[tid] = cnt;
    __syncthreads();
    for (int s = 1; s < 256; s <<= 1) {
        int v = (tid >= s) ? scan[tid - s] : 0;
        __syncthreads();
        scan[tid] += v;
        __syncthreads();
    }
    if (tid == 255) sbase = atomicAdd(WLn, (unsigned int)scan[255]);
    __syncthreads();

    if (r < NPATCH) {
        unsigned int w = sbase + (unsigned int)(scan[tid] - cnt);
        for (int t = 0; t < NT; ++t)
            if ((float)cachev[t][tid] >= thr)
                WL[w++] = ((unsigned int)r << 7) | (unsigned int)t;
    }
}

// ---------- repair: 2 items/wave, branch-free fused eval
__global__ __launch_bounds__(256)
void repair_items(const float* __restrict__ crop, const float* __restrict__ orig,
                  const float* __restrict__ X2, const float* __restrict__ Y2,
                  const unsigned int* __restrict__ WL, const unsigned int* __restrict__ WLn,
                  unsigned long long* __restrict__ RES) {
    const int lane = threadIdx.x & 63;
    const unsigned int gw = (blockIdx.x * 256 + threadIdx.x) >> 6;
    const unsigned int nw = (gridDim.x * 256) >> 6;
    const unsigned int n = *WLn;
    const unsigned int npairs = (n + 1) >> 1;

    for (unsigned int p = gw; p < npairs; p += nw) {
        const unsigned int i0 = 2 * p;
        const unsigned int i1 = (2 * p + 1 < n) ? (2 * p + 1) : i0;
        const unsigned int item0 = __builtin_amdgcn_readfirstlane(WL[i0]);
        const unsigned int item1 = __builtin_amdgcn_readfirstlane(WL[i1]);

        const int r0 = (int)(item0 >> 7), tl0 = (int)(item0 & 127u);
        const int r1 = (int)(item1 >> 7), tl1 = (int)(item1 & 127u);
        const int pr0 = r0 / 124, pc0 = r0 - pr0 * 124;
        const int pr1 = r1 / 124, pc1 = r1 - pr1 * 124;
        const float* xb0 = crop + pr0 * 128 + pc0;
        const float* xb1 = crop + pr1 * 128 + pc1;
        const float x20 = X2[r0], x21 = X2[r1];

        const int j00 = min(tl0 * 128 + lane,      NPATCH - 1);
        const int j01 = min(tl0 * 128 + 64 + lane, NPATCH - 1);
        const int j10 = min(tl1 * 128 + lane,      NPATCH - 1);
        const int j11 = min(tl1 * 128 + 64 + lane, NPATCH - 1);
        const float* y00 = orig + (j00 / 124) * 128 + (j00 % 124);
        const float* y01 = orig + (j01 / 124) * 128 + (j01 % 124);
        const float* y10 = orig + (j10 / 124) * 128 + (j10 % 124);
        const float* y11 = orig + (j11 / 124) * 128 + (j11 % 124);

        float d00 = 0.f, d01 = 0.f, d10 = 0.f, d11 = 0.f;
        #pragma unroll
        for (int ch = 0; ch < 3; ++ch) {
            #pragma unroll
            for (int di = 0; di < 5; ++di) {
                const int o = ch * 16384 + di * 128;
                const f32x4u v00 = *(const f32x4u*)(y00 + o);
                const f32x4u v01 = *(const f32x4u*)(y01 + o);
                const f32x4u v10 = *(const f32x4u*)(y10 + o);
                const f32x4u v11 = *(const f32x4u*)(y11 + o);
                const float w00 = y00[o + 4], w01 = y01[o + 4];
                const float w10 = y10[o + 4], w11 = y11[o + 4];
                const float xa0 = xb0[o], xa1 = xb0[o + 1], xa2 = xb0[o + 2],
                            xa3 = xb0[o + 3], xa4 = xb0[o + 4];
                const float xc0 = xb1[o], xc1 = xb1[o + 1], xc2 = xb1[o + 2],
                            xc3 = xb1[o + 3], xc4 = xb1[o + 4];
                d00 = fmaf(xa0, v00.x, d00); d01 = fmaf(xa0, v01.x, d01);
                d10 = fmaf(xc0, v10.x, d10); d11 = fmaf(xc0, v11.x, d11);
                d00 = fmaf(xa1, v00.y, d00); d01 = fmaf(xa1, v01.y, d01);
                d10 = fmaf(xc1, v10.y, d10); d11 = fmaf(xc1, v11.y, d11);
                d00 = fmaf(xa2, v00.z, d00); d01 = fmaf(xa2, v01.z, d01);
                d10 = fmaf(xc2, v10.z, d10); d11 = fmaf(xc2, v11.z, d11);
                d00 = fmaf(xa3, v00.w, d00); d01 = fmaf(xa3, v01.w, d01);
                d10 = fmaf(xc3, v10.w, d10); d11 = fmaf(xc3, v11.w, d11);
                d00 = fmaf(xa4, w00, d00);   d01 = fmaf(xa4, w01, d01);
                d10 = fmaf(xc4, w10, d10);   d11 = fmaf(xc4, w11, d11);
            }
        }
        const float e00 = fmaf(-2.f, d00, x20) + Y2[j00];
        const float e01 = fmaf(-2.f, d01, x20) + Y2[j01];
        const float e10 = fmaf(-2.f, d10, x21) + Y2[j10];
        const float e11 = fmaf(-2.f, d11, x21) + Y2[j11];

        const bool s0 = (e01 < e00) || (e01 == e00 && j01 < j00);
        const bool s1 = (e11 < e10) || (e11 == e10 && j11 < j10);
        float bd0 = s0 ? e01 : e00;  int bj0 = s0 ? j01 : j00;
        float bd1 = s1 ? e11 : e10;  int bj1 = s1 ? j11 : j10;

        float dm0 = bd0, dm1 = bd1;
        #pragma unroll
        for (int off = 1; off < 64; off <<= 1) {
            dm0 = fminf(dm0, __shfl_xor(dm0, off));
            dm1 = fminf(dm1, __shfl_xor(dm1, off));
        }
        int jc0 = (bd0 == dm0) ? bj0 : 0x7fffffff;
        int jc1 = (bd1 == dm1) ? bj1 : 0x7fffffff;
        #pragma unroll
        for (int off = 1; off < 64; off <<= 1) {
            jc0 = min(jc0, __shfl_xor(jc0, off));
            jc1 = min(jc1, __shfl_xor(jc1, off));
        }
        if (lane == 0) {
            atomicMin(RES + r0, (((unsigned long long)fsort(dm0)) << 32) | (unsigned int)jc0);
            atomicMin(RES + r1, (((unsigned long long)fsort(dm1)) << 32) | (unsigned int)jc1);
        }
    }
}

// ---------- finalize: unpack RES -> out idx + rsum
__global__ void finalize_kernel(const unsigned long long* __restrict__ RES,
                                float* __restrict__ out, float* __restrict__ rsum) {
    int r = blockIdx.x * 256 + threadIdx.x;
    if (r >= NPATCH) return;
    unsigned long long v = RES[r];
    unsigned int j = (unsigned int)v;
    unsigned int u = (unsigned int)(v >> 32);
    unsigned int b = (u & 0x80000000u) ? (u ^ 0x80000000u) : ~u;
    out[1 + r] = (float)j;
    rsum[r] = __builtin_bit_cast(float, b);
}

// ---------- deterministic final loss
__global__ void loss_final(const float* __restrict__ rsum, float* __restrict__ out) {
    __shared__ float s[256];
    float acc = 0.f;
    for (int i = threadIdx.x; i < NPATCH; i += 256) acc += rsum[i];
    s[threadIdx.x] = acc;
    __syncthreads();
    for (int st = 128; st > 0; st >>= 1) {
        if (threadIdx.x < st) s[threadIdx.x] += s[threadIdx.x + st];
        __syncthreads();
    }
    if (threadIdx.x == 0) out[0] = s[0] / (float)NPATCH;
}

extern "C" void kernel_launch(void* const* d_in, const int* in_sizes, int n_in,
                              void* d_out, int out_size, void* d_ws, size_t ws_size,
                              hipStream_t stream) {
    const float* crop = (const float*)d_in[0];
    const float* orig = (const float*)d_in[1];
    float* out = (float*)d_out;

    unsigned short* Abig = (unsigned short*)d_ws;                     // 3.15 MB
    unsigned short* Bbig = Abig + (size_t)ATILES * TILE_SHORTS;       // 2.97 MB
    _Float16* PMh = (_Float16*)(Bbig + (size_t)NT * TILE_SHORTS);     // 242*16384*2 = 7.93 MB
    float* X2 = (float*)(PMh + (size_t)242 * PMSTR);                  // 61.5 KB
    float* Y2 = X2 + NPATCH;                                          // 62 KB
    unsigned long long* RES = (unsigned long long*)(Y2 + NP);         // 123 KB
    float* RS = (float*)(RES + NPATCH);                               // 61.5 KB
    unsigned int* WLn = (unsigned int*)(RS + NPATCH);                 // 64 B
    unsigned int* WL = WLn + 16;                                      // 7.44 MB (worst case)
                                                                      // total ~= 21.8 MB

    sqnorm2<<<(NP + NPATCH + 255) / 256, 256, 0, stream>>>(crop, orig, X2, Y2, WLn, RES);
    pack2<<<(ATILES + NT) * 6, 256, 0, stream>>>(crop, orig, Abig, Bbig, Y2);
    dist_mfma6<<<1024, 256, 0, stream>>>(Abig, Bbig, PMh);
    flag_kernel<<<(NPATCH + 255) / 256, 256, 0, stream>>>(PMh, WL, WLn);
    repair_items<<<2048, 256, 0, stream>>>(crop, orig, X2, Y2, WL, WLn, RES);
    finalize_kernel<<<(NPATCH + 255) / 256, 256, 0, stream>>>(RES, out, RS);
    loss_final<<<1, 256, 0, stream>>>(RS, out);
}

// Round 24
// 136.007 us; speedup vs baseline: 1.5225x; 1.5225x over previous
//
#include <hip/hip_runtime.h>
#include <hip/hip_bf16.h>

#define NPATCH 15376       // 124*124 patches
#define NP     15488       // B rows padded: 121*128
#define NT     121         // B col-tiles (128 each)
#define ATILES 128         // A rows padded: 128*128 = 16384
#define TILE_SHORTS 12288  // 12*128*8 shorts per 128-row tile (24KB)
#define EPSA   1.30f       // acc-space margin; rigorous 2E ~= 1.16 (bf16 screen + f16 PM)
#define PMSTR  16384       // PMh row stride

typedef __attribute__((ext_vector_type(8))) __bf16 bf16x8;
typedef __attribute__((ext_vector_type(4))) float  f32x4;
typedef __attribute__((ext_vector_type(4))) _Float16 f16x4;
typedef float __attribute__((ext_vector_type(4), aligned(4))) f32x4u;  // 4B-aligned vec load

__device__ __forceinline__ unsigned short f2bf(float x) {
    __hip_bfloat16 h = __float2bfloat16(x);
    return *(unsigned short*)&h;
}
__device__ __forceinline__ float bf2f(unsigned short u) {
    __hip_bfloat16 h; *(unsigned short*)&h = u;
    return __bfloat162float(h);
}
__device__ __forceinline__ unsigned int fsort(float d) {   // monotone float->uint
    unsigned int b = __builtin_bit_cast(unsigned int, d);
    return (b & 0x80000000u) ? ~b : (b | 0x80000000u);
}
__device__ __forceinline__ float max3f(float a, float b, float c) {
    return fmaxf(fmaxf(a, b), c);   // clang fuses to v_max3_f32
}

// ---------- fused squared norms + RES/WLn init
__device__ __forceinline__ float patch_sq(const float* __restrict__ img, int p) {
    int pr = p / 124, pc = p - pr * 124;
    const float* base = img + pr * 128 + pc;
    float s = 0.f;
    #pragma unroll
    for (int ch = 0; ch < 3; ++ch)
        #pragma unroll
        for (int di = 0; di < 5; ++di)
            #pragma unroll
            for (int dj = 0; dj < 5; ++dj) {
                float v = base[ch * 16384 + di * 128 + dj];
                s = fmaf(v, v, s);
            }
    return s;
}
__global__ void sqnorm2(const float* __restrict__ crop, const float* __restrict__ orig,
                        float* __restrict__ X2, float* __restrict__ Y2,
                        unsigned int* __restrict__ WLn, unsigned long long* __restrict__ RES) {
    int p = blockIdx.x * 256 + threadIdx.x;
    if (p == 0) *WLn = 0;
    if (p < NP) {
        Y2[p] = (p < NPATCH) ? patch_sq(orig, p) : 3.0e38f;
    } else {
        int q = p - NP;
        if (q < NPATCH) { X2[q] = patch_sq(crop, q); RES[q] = 0xFFFFFFFFFFFFFFFFULL; }
    }
}

// ---------- pack both matrices: tile-major [tile][kslot12][row128][8] bf16.
__global__ void pack2(const float* __restrict__ crop, const float* __restrict__ orig,
                      unsigned short* __restrict__ Abig, unsigned short* __restrict__ Bbig,
                      const float* __restrict__ Y2) {
    int cid = blockIdx.x * 256 + threadIdx.x;
    const float* img;
    unsigned short* dst;
    bool isA;
    if (cid < ATILES * 1536) { img = crop; dst = Abig; isA = true; }
    else { cid -= ATILES * 1536; img = orig; dst = Bbig; isA = false; }
    int t = cid / 1536, rem = cid - t * 1536;
    int s = rem >> 7, r = rem & 127;
    int row = t * 128 + r;
    unsigned short ch8[8];
    #pragma unroll
    for (int e = 0; e < 8; ++e) {
        int k = s * 8 + e;
        unsigned short v = 0;
        if (k < 75) {
            if (row < NPATCH) {
                int c = k / 25, rem2 = k - c * 25;
                int di = rem2 / 5, dj = rem2 - di * 5;
                int pr = row / 124, pc = row - pr * 124;
                v = f2bf(img[c * 16384 + (pr + di) * 128 + (pc + dj)]);
            }
        } else if (k < 77) {
            if (isA) v = f2bf(-0.5f);
            else {
                float yv = Y2[row];
                unsigned short hi = f2bf(yv);
                v = (k == 75) ? hi : f2bf(yv - bf2f(hi));
            }
        }
        ch8[e] = v;
    }
    *(ulonglong2*)(dst + (size_t)cid * 8) = *(ulonglong2*)ch8;
}

// ---------- MFMA screen, barrier-free; 4 waves/block SHARE the same B stream (L1 reuse)
__global__ __launch_bounds__(256, 2)
void dist_mfma6(const unsigned short* __restrict__ A, const unsigned short* __restrict__ B,
                _Float16* __restrict__ PMh) {
    __shared__ _Float16 stash[4][16][64];   // 8 KB, wave-private slices: no barriers

    const int tid = threadIdx.x, lane = tid & 63, wid = tid >> 6;
    const int l15 = lane & 15, l4 = lane >> 4;

    const int b = blockIdx.x;                    // 0..1023
    const int cg = b & 1;
    const int chunk = (b >> 1) & 7;
    const int rowgroup = (b >> 4) * 4 + wid;     // 0..255 (64 rows each)
    const int t0 = chunk * 15 + (chunk ? 1 : 0);
    const int nt = chunk ? 15 : 16;              // 16 + 15*7 = 121

    bf16x8 a[4][3];
    {
        const int atile = rowgroup >> 1, rbase = (rowgroup & 1) * 64;
        const unsigned short* Ab =
            A + ((size_t)atile * 12 + l4) * 1024 + (size_t)(rbase + l15) * 8;
        #pragma unroll
        for (int mi = 0; mi < 4; ++mi)
            #pragma unroll
            for (int k3 = 0; k3 < 3; ++k3)
                a[mi][k3] = *(const bf16x8*)(Ab + k3 * 4096 + mi * 128);
    }

    const size_t cgofs = (size_t)cg * 512 + (size_t)l15 * 8;
    bf16x8 b0[12], b1[12];

#define BLOAD(bank, tile)                                                         \
    {                                                                             \
        const unsigned short* _B = B + ((size_t)(tile) * 12 + l4) * 1024 + cgofs; \
        _Pragma("unroll")                                                         \
        for (int _ni = 0; _ni < 4; ++_ni)                                         \
            _Pragma("unroll")                                                     \
            for (int _k3 = 0; _k3 < 3; ++_k3)                                     \
                bank[_ni * 3 + _k3] = *(const bf16x8*)(_B + _k3 * 4096 + _ni * 128); \
    }

#define COMPUTE(bank, it)                                                         \
    {                                                                             \
        f32x4 acc[4][4];                                                          \
        _Pragma("unroll")                                                         \
        for (int _k3 = 0; _k3 < 3; ++_k3)                                         \
            _Pragma("unroll")                                                     \
            for (int _mi = 0; _mi < 4; ++_mi)                                     \
                _Pragma("unroll")                                                 \
                for (int _ni = 0; _ni < 4; ++_ni)                                 \
                    acc[_mi][_ni] = __builtin_amdgcn_mfma_f32_16x16x32_bf16(      \
                        bank[_ni * 3 + _k3], a[_mi][_k3],                         \
                        (_k3 == 0) ? (f32x4){0.f, 0.f, 0.f, 0.f} : acc[_mi][_ni], \
                        0, 0, 0);                                                 \
        _Pragma("unroll")                                                         \
        for (int _mi = 0; _mi < 4; ++_mi) {                                       \
            float _t0 = max3f(acc[_mi][0][0], acc[_mi][0][1], acc[_mi][0][2]);    \
            float _t1 = max3f(acc[_mi][0][3], acc[_mi][1][0], acc[_mi][1][1]);    \
            float _t2 = max3f(acc[_mi][1][2], acc[_mi][1][3], acc[_mi][2][0]);    \
            float _t3 = max3f(acc[_mi][2][1], acc[_mi][2][2], acc[_mi][2][3]);    \
            float _t4 = max3f(acc[_mi][3][0], acc[_mi][3][1], acc[_mi][3][2]);    \
            float _u0 = max3f(_t0, _t1, acc[_mi][3][3]);                          \
            float _u1 = max3f(_t2, _t3, _t4);                                     \
            float _m  = fmaxf(_u0, _u1);                                          \
            _m = fmaxf(_m, __shfl_xor(_m, 16));                                   \
            _m = fmaxf(_m, __shfl_xor(_m, 32));                                   \
            if (l4 == 0) stash[wid][it][_mi * 16 + l15] = (_Float16)_m;           \
        }                                                                         \
    }

    BLOAD(b0, t0);
    int it = 0;
    while (true) {
        if (it + 1 < nt) BLOAD(b1, t0 + it + 1);
        COMPUTE(b0, it);
        ++it;
        if (it >= nt) break;
        if (it + 1 < nt) BLOAD(b0, t0 + it + 1);
        COMPUTE(b1, it);
        ++it;
        if (it >= nt) break;
    }
#undef BLOAD
#undef COMPUTE

    for (int i2 = 0; i2 < nt; ++i2)
        PMh[(size_t)((t0 + i2) * 2 + cg) * PMSTR + rowgroup * 64 + lane] = stash[wid][i2][lane];
}

// ---------- flag: block = 256 rows; coalesced PMh reads; ONE global atomic per block
__global__ __launch_bounds__(256)
void flag_kernel(const _Float16* __restrict__ PMh,
                 unsigned int* __restrict__ WL, unsigned int* __restrict__ WLn) {
    __shared__ _Float16 cachev[NT][256];   // 61.9 KB (folded tile maxima)
    __shared__ int scan[256];
    __shared__ unsigned int sbase;

    const int tid = threadIdx.x;
    const int r = blockIdx.x * 256 + tid;
    const int rr = (r < NPATCH) ? r : (NPATCH - 1);

    float mt = -3.4e38f;
    for (int t = 0; t < NT; ++t) {
        float v0 = (float)PMh[(size_t)(2 * t) * PMSTR + rr];
        float v1 = (float)PMh[(size_t)(2 * t + 1) * PMSTR + rr];
        float v = fmaxf(v0, v1);
        cachev[t][tid] = (_Float16)v;
        mt = fmaxf(mt, v);
    }
    const float thr = mt - EPSA;

    int cnt = 0;
    if (r < NPATCH)
        for (int t = 0; t < NT; ++t)
            cnt += ((float)cachev[t][tid] >= thr) ? 1 : 0;

    scan[tid] = cnt;
    __syncthreads();
    for (int s = 1; s < 256; s <<= 1) {
        int v = (tid >= s) ? scan[tid - s] : 0;
        __syncthreads();
        scan[tid] += v;
        __syncthreads();
    }
    if (tid == 255) sbase = atomicAdd(WLn, (unsigned int)scan[255]);
    __syncthreads();

    if (r < NPATCH) {
        unsigned int w = sbase + (unsigned int)(scan[tid] - cnt);
        for (int t = 0; t < NT; ++t)
            if ((float)cachev[t][tid] >= thr)
                WL[w++] = ((unsigned int)r << 7) | (unsigned int)t;
    }
}

// ---------- repair: 2 items/wave, branch-free fused eval
__global__ __launch_bounds__(256)
void repair_items(const float* __restrict__ crop, const float* __restrict__ orig,
                  const float* __restrict__ X2, const float* __restrict__ Y2,
                  const unsigned int* __restrict__ WL, const unsigned int* __restrict__ WLn,
                  unsigned long long* __restrict__ RES) {
    const int lane = threadIdx.x & 63;
    const unsigned int gw = (blockIdx.x * 256 + threadIdx.x) >> 6;
    const unsigned int nw = (gridDim.x * 256) >> 6;
    const unsigned int n = *WLn;
    const unsigned int npairs = (n + 1) >> 1;

    for (unsigned int p = gw; p < npairs; p += nw) {
        const unsigned int i0 = 2 * p;
        const unsigned int i1 = (2 * p + 1 < n) ? (2 * p + 1) : i0;
        const unsigned int item0 = __builtin_amdgcn_readfirstlane(WL[i0]);
        const unsigned int item1 = __builtin_amdgcn_readfirstlane(WL[i1]);

        const int r0 = (int)(item0 >> 7), tl0 = (int)(item0 & 127u);
        const int r1 = (int)(item1 >> 7), tl1 = (int)(item1 & 127u);
        const int pr0 = r0 / 124, pc0 = r0 - pr0 * 124;
        const int pr1 = r1 / 124, pc1 = r1 - pr1 * 124;
        const float* xb0 = crop + pr0 * 128 + pc0;
        const float* xb1 = crop + pr1 * 128 + pc1;
        const float x20 = X2[r0], x21 = X2[r1];

        const int j00 = min(tl0 * 128 + lane,      NPATCH - 1);
        const int j01 = min(tl0 * 128 + 64 + lane, NPATCH - 1);
        const int j10 = min(tl1 * 128 + lane,      NPATCH - 1);
        const int j11 = min(tl1 * 128 + 64 + lane, NPATCH - 1);
        const float* y00 = orig + (j00 / 124) * 128 + (j00 % 124);
        const float* y01 = orig + (j01 / 124) * 128 + (j01 % 124);
        const float* y10 = orig + (j10 / 124) * 128 + (j10 % 124);
        const float* y11 = orig + (j11 / 124) * 128 + (j11 % 124);

        float d00 = 0.f, d01 = 0.f, d10 = 0.f, d11 = 0.f;
        #pragma unroll
        for (int ch = 0; ch < 3; ++ch) {
            #pragma unroll
            for (int di = 0; di < 5; ++di) {
                const int o = ch * 16384 + di * 128;
                const f32x4u v00 = *(const f32x4u*)(y00 + o);
                const f32x4u v01 = *(const f32x4u*)(y01 + o);
                const f32x4u v10 = *(const f32x4u*)(y10 + o);
                const f32x4u v11 = *(const f32x4u*)(y11 + o);
                const float w00 = y00[o + 4], w01 = y01[o + 4];
                const float w10 = y10[o + 4], w11 = y11[o + 4];
                const float xa0 = xb0[o], xa1 = xb0[o + 1], xa2 = xb0[o + 2],
                            xa3 = xb0[o + 3], xa4 = xb0[o + 4];
                const float xc0 = xb1[o], xc1 = xb1[o + 1], xc2 = xb1[o + 2],
                            xc3 = xb1[o + 3], xc4 = xb1[o + 4];
                d00 = fmaf(xa0, v00.x, d00); d01 = fmaf(xa0, v01.x, d01);
                d10 = fmaf(xc0, v10.x, d10); d11 = fmaf(xc0, v11.x, d11);
                d00 = fmaf(xa1, v00.y, d00); d01 = fmaf(xa1, v01.y, d01);
                d10 = fmaf(xc1, v10.y, d10); d11 = fmaf(xc1, v11.y, d11);
                d00 = fmaf(xa2, v00.z, d00); d01 = fmaf(xa2, v01.z, d01);
                d10 = fmaf(xc2, v10.z, d10); d11 = fmaf(xc2, v11.z, d11);
                d00 = fmaf(xa3, v00.w, d00); d01 = fmaf(xa3, v01.w, d01);
                d10 = fmaf(xc3, v10.w, d10); d11 = fmaf(xc3, v11.w, d11);
                d00 = fmaf(xa4, w00, d00);   d01 = fmaf(xa4, w01, d01);
                d10 = fmaf(xc4, w10, d10);   d11 = fmaf(xc4, w11, d11);
            }
        }
        const float e00 = fmaf(-2.f, d00, x20) + Y2[j00];
        const float e01 = fmaf(-2.f, d01, x20) + Y2[j01];
        const float e10 = fmaf(-2.f, d10, x21) + Y2[j10];
        const float e11 = fmaf(-2.f, d11, x21) + Y2[j11];

        const bool s0 = (e01 < e00) || (e01 == e00 && j01 < j00);
        const bool s1 = (e11 < e10) || (e11 == e10 && j11 < j10);
        float bd0 = s0 ? e01 : e00;  int bj0 = s0 ? j01 : j00;
        float bd1 = s1 ? e11 : e10;  int bj1 = s1 ? j11 : j10;

        float dm0 = bd0, dm1 = bd1;
        #pragma unroll
        for (int off = 1; off < 64; off <<= 1) {
            dm0 = fminf(dm0, __shfl_xor(dm0, off));
            dm1 = fminf(dm1, __shfl_xor(dm1, off));
        }
        int jc0 = (bd0 == dm0) ? bj0 : 0x7fffffff;
        int jc1 = (bd1 == dm1) ? bj1 : 0x7fffffff;
        #pragma unroll
        for (int off = 1; off < 64; off <<= 1) {
            jc0 = min(jc0, __shfl_xor(jc0, off));
            jc1 = min(jc1, __shfl_xor(jc1, off));
        }
        if (lane == 0) {
            atomicMin(RES + r0, (((unsigned long long)fsort(dm0)) << 32) | (unsigned int)jc0);
            atomicMin(RES + r1, (((unsigned long long)fsort(dm1)) << 32) | (unsigned int)jc1);
        }
    }
}

// ---------- finalize: unpack RES -> out idx + rsum
__global__ void finalize_kernel(const unsigned long long* __restrict__ RES,
                                float* __restrict__ out, float* __restrict__ rsum) {
    int r = blockIdx.x * 256 + threadIdx.x;
    if (r >= NPATCH) return;
    unsigned long long v = RES[r];
    unsigned int j = (unsigned int)v;
    unsigned int u = (unsigned int)(v >> 32);
    unsigned int b = (u & 0x80000000u) ? (u ^ 0x80000000u) : ~u;
    out[1 + r] = (float)j;
    rsum[r] = __builtin_bit_cast(float, b);
}

// ---------- deterministic final loss
__global__ void loss_final(const float* __restrict__ rsum, float* __restrict__ out) {
    __shared__ float s[256];
    float acc = 0.f;
    for (int i = threadIdx.x; i < NPATCH; i += 256) acc += rsum[i];
    s[threadIdx.x] = acc;
    __syncthreads();
    for (int st = 128; st > 0; st >>= 1) {
        if (threadIdx.x < st) s[threadIdx.x] += s[threadIdx.x + st];
        __syncthreads();
    }
    if (threadIdx.x == 0) out[0] = s[0] / (float)NPATCH;
}

extern "C" void kernel_launch(void* const* d_in, const int* in_sizes, int n_in,
                              void* d_out, int out_size, void* d_ws, size_t ws_size,
                              hipStream_t stream) {
    const float* crop = (const float*)d_in[0];
    const float* orig = (const float*)d_in[1];
    float* out = (float*)d_out;

    unsigned short* Abig = (unsigned short*)d_ws;                     // 3.15 MB
    unsigned short* Bbig = Abig + (size_t)ATILES * TILE_SHORTS;       // 2.97 MB
    _Float16* PMh = (_Float16*)(Bbig + (size_t)NT * TILE_SHORTS);     // 242*16384*2 = 7.93 MB
    float* X2 = (float*)(PMh + (size_t)242 * PMSTR);                  // 61.5 KB
    float* Y2 = X2 + NPATCH;                                          // 62 KB
    unsigned long long* RES = (unsigned long long*)(Y2 + NP);         // 123 KB
    float* RS = (float*)(RES + NPATCH);                               // 61.5 KB
    unsigned int* WLn = (unsigned int*)(RS + NPATCH);                 // 64 B
    unsigned int* WL = WLn + 16;                                      // 7.44 MB (worst case)
                                                                      // total ~= 21.8 MB

    sqnorm2<<<(NP + NPATCH + 255) / 256, 256, 0, stream>>>(crop, orig, X2, Y2, WLn, RES);
    pack2<<<(ATILES + NT) * 6, 256, 0, stream>>>(crop, orig, Abig, Bbig, Y2);
    dist_mfma6<<<1024, 256, 0, stream>>>(Abig, Bbig, PMh);
    flag_kernel<<<(NPATCH + 255) / 256, 256, 0, stream>>>(PMh, WL, WLn);
    repair_items<<<2048, 256, 0, stream>>>(crop, orig, X2, Y2, WL, WLn, RES);
    finalize_kernel<<<(NPATCH + 255) / 256, 256, 0, stream>>>(RES, out, RS);
    loss_final<<<1, 256, 0, stream>>>(RS, out);
}